// Round 4
// baseline (361.900 us; speedup 1.0000x reference)
//
#include <hip/hip_runtime.h>
#include <hip/hip_bf16.h>
#include <stdint.h>

// DequantingLinear: out[TOK,OUT] = x[TOK,IN] @ dequant(w_q,w_scales)^T + bias
// R4: 8-phase 256x256 BK=64 with unit-reordered LDS so each phase reads
// exactly 2 stage-units; 1 stage-unit (2 gload_lds) issued per phase;
// vmcnt(4) at 6 of 8 phase-ends (2-phase min lead, 2 units always in flight).

typedef __bf16 bf16;
typedef __bf16 bf16x8 __attribute__((ext_vector_type(8)));
typedef float f32x4 __attribute__((ext_vector_type(4)));

#define AS1 __attribute__((address_space(1)))
#define AS3 __attribute__((address_space(3)))

__device__ __forceinline__ void gload_lds16(const void* g, void* l) {
    __builtin_amdgcn_global_load_lds((AS1 void*)g, (AS3 void*)l, 16, 0, 0);
}

#define MFMA16(d, x, y) d = __builtin_amdgcn_mfma_f32_16x16x32_bf16(x, y, d, 0, 0, 0)

// ---------------- Pass 1a: dequantize w_q (int32) * scale -> bf16 ----------
__global__ __launch_bounds__(128) void k_dequant(
    const int* __restrict__ q, const float* __restrict__ sc,
    bf16* __restrict__ w, int IN) {
    const int row = blockIdx.y;
    const int k = (blockIdx.x * 128 + threadIdx.x) * 8;
    if (k >= IN) return;
    const float s = sc[(size_t)row * (IN >> 5) + (k >> 5)];
    const size_t base = (size_t)row * IN + k;
    const int4 q0 = *(const int4*)(q + base);
    const int4 q1 = *(const int4*)(q + base + 4);
    bf16x8 o;
    o[0] = (bf16)(q0.x * s); o[1] = (bf16)(q0.y * s);
    o[2] = (bf16)(q0.z * s); o[3] = (bf16)(q0.w * s);
    o[4] = (bf16)(q1.x * s); o[5] = (bf16)(q1.y * s);
    o[6] = (bf16)(q1.z * s); o[7] = (bf16)(q1.w * s);
    *(bf16x8*)(w + base) = o;
}

// ---------------- Pass 1b: x f32 -> bf16 -----------------------------------
__global__ __launch_bounds__(256) void k_cvt(
    const float* __restrict__ x, bf16* __restrict__ xb, long long n8) {
    long long i = (long long)blockIdx.x * 256 + threadIdx.x;
    const long long stride = (long long)gridDim.x * 256;
    for (; i < n8; i += stride) {
        const float4 a = *(const float4*)(x + i * 8);
        const float4 b = *(const float4*)(x + i * 8 + 4);
        bf16x8 o;
        o[0] = (bf16)a.x; o[1] = (bf16)a.y; o[2] = (bf16)a.z; o[3] = (bf16)a.w;
        o[4] = (bf16)b.x; o[5] = (bf16)b.y; o[6] = (bf16)b.z; o[7] = (bf16)b.w;
        *(bf16x8*)(xb + i * 8) = o;
    }
}

// ---------------- Pass 2: 256x256 bf16 GEMM, 8-phase, unit-reordered LDS ---
// 512 thr = 8 waves (wm=wv>>2 in {0,1}, wn=wv&3 in {0..3}); wave out 128x64.
// Per buf (64KB): A units A_h at h*16384 (LDS row = h*128 + wm*64 + j <->
// logical row wm*128 + h*64 + j); B units B_c at 32768 + c*16384 (LDS row =
// c*128 + g*32 + i <-> logical row g*64 + c*32 + i). Phase (h,c) reads only
// {A_h, B_c}. Quadrant order (0,0),(0,1),(1,1),(1,0). One unit staged per
// phase; vmcnt(4) at ends of ph0,1,3,4,5,7.
__global__ __launch_bounds__(512, 2) void k_gemm8p(
    const bf16* __restrict__ A, const bf16* __restrict__ B,
    const float* __restrict__ bias, float* __restrict__ C,
    int M, int N, int K) {
    __shared__ __align__(16) char lds[131072];
    const int tid = threadIdx.x;
    const int wv = tid >> 6, ln = tid & 63;
    const int wm = wv >> 2, wn = wv & 3;
    const int nbn = N >> 8;
    const int nwg = gridDim.x;
    const int q8 = nwg >> 3, r8 = nwg & 7;
    const int xcd = blockIdx.x & 7, lin = blockIdx.x >> 3;
    const int swz = (xcd < r8 ? xcd * (q8 + 1)
                              : r8 * (q8 + 1) + (xcd - r8) * q8) + lin;
    const int bm = swz / nbn, bn = swz % nbn;

    const size_t rowb = (size_t)K * 2;
    // XOR swizzle: LDS slot (tid&7) holds logical col chunk (tid&7)^(ldsrow&7)
    const int scol = (((tid ^ (tid >> 3)) & 7) << 4);
    // A stage base: logical row (tid>>3) within a 128-row block
    const char* Ag = (const char*)A + ((size_t)(bm << 8) + (tid >> 3)) * rowb + scol;
    // B stage base: logical row (tid>>8)*64 + ((tid>>3)&31) within 128-row block
    const char* Bg = (const char*)B +
        ((size_t)(bn << 8) + ((tid >> 8) << 6) + ((tid >> 3) & 31)) * rowb + scol;
    const int ldsw = wv << 10;

    // stage unit A_h of tile at kt into buf bb_ (call k covers logical rows
    // k*128 + h*64 + (tid>>3), LDS rows h*128 + k*64 + (tid>>3))
#define STGA(bb_, h_, kt_) do {                                               \
        const size_t kb_ = (size_t)(kt_) << 1;                                \
        gload_lds16(Ag + (size_t)((h_) << 6) * rowb + kb_,                    \
                    lds + (bb_) + ((h_) << 14) + ldsw);                       \
        gload_lds16(Ag + (size_t)(128 + ((h_) << 6)) * rowb + kb_,            \
                    lds + (bb_) + ((h_) << 14) + 8192 + ldsw);                \
    } while (0)
    // stage unit B_c (call k: logical rows k*128 + (tid>>8)*64 + c*32 + i)
#define STGB(bb_, c_, kt_) do {                                               \
        const size_t kb_ = (size_t)(kt_) << 1;                                \
        gload_lds16(Bg + (size_t)((c_) << 5) * rowb + kb_,                    \
                    lds + (bb_) + 32768 + ((c_) << 14) + ldsw);               \
        gload_lds16(Bg + (size_t)(128 + ((c_) << 5)) * rowb + kb_,            \
                    lds + (bb_) + 32768 + ((c_) << 14) + 8192 + ldsw);        \
    } while (0)

    // swizzled column bytes for kslice 0/1 (row&7 == ln&7)
    const int colx = ((ln & 4) << 4) | ((((ln >> 4) ^ ln) & 3) << 4);
    const int c0 = colx, c1 = colx ^ 64;
    const int arow = (wm << 13) + ((ln & 15) << 7);  // wm*64 rows + lane row
    const int brow = (wn << 12) + ((ln & 15) << 7);  // wn*32 rows + lane row

    f32x4 acc[8][4] = {};

#define SB __builtin_amdgcn_sched_barrier(0)
#define BAR __builtin_amdgcn_s_barrier()
#define EW4 do { asm volatile("s_waitcnt vmcnt(4)" ::: "memory"); SB; BAR; SB; } while (0)
#define EW2 do { asm volatile("s_waitcnt vmcnt(2)" ::: "memory"); SB; BAR; SB; } while (0)
#define EW0 do { asm volatile("s_waitcnt vmcnt(0)" ::: "memory"); SB; BAR; SB; } while (0)
#define EWN do { BAR; SB; } while (0)

#define PHASE(bb_, h_, c_, STAGE_STMT, ENDW_STMT) do {                        \
        const char* uA_ = lds + (bb_) + ((h_) << 14);                         \
        const char* uB_ = lds + (bb_) + 32768 + ((c_) << 14);                 \
        bf16x8 paf[8], pbf[4];                                                \
        _Pragma("unroll")                                                     \
        for (int r = 0; r < 4; ++r) {                                         \
            paf[r*2+0] = *(const bf16x8*)(uA_ + arow + (r << 11) + c0);       \
            paf[r*2+1] = *(const bf16x8*)(uA_ + arow + (r << 11) + c1);       \
        }                                                                     \
        _Pragma("unroll")                                                     \
        for (int rb = 0; rb < 2; ++rb) {                                      \
            pbf[rb*2+0] = *(const bf16x8*)(uB_ + brow + (rb << 11) + c0);     \
            pbf[rb*2+1] = *(const bf16x8*)(uB_ + brow + (rb << 11) + c1);     \
        }                                                                     \
        STAGE_STMT;                                                           \
        BAR;                                                                  \
        __builtin_amdgcn_s_setprio(1);                                        \
        _Pragma("unroll")                                                     \
        for (int r = 0; r < 4; ++r)                                           \
            _Pragma("unroll")                                                 \
            for (int rb = 0; rb < 2; ++rb) {                                  \
                MFMA16(acc[(h_)*4+r][(c_)*2+rb], paf[r*2+0], pbf[rb*2+0]);    \
                MFMA16(acc[(h_)*4+r][(c_)*2+rb], paf[r*2+1], pbf[rb*2+1]);    \
            }                                                                 \
        __builtin_amdgcn_s_setprio(0);                                        \
        ENDW_STMT;                                                            \
    } while (0)

    // ---- prologue: tile0 -> buf0 (A0,B0,B1,A1); drain A0,B0, keep B1,A1
    STGA(0, 0, 0);
    STGB(0, 0, 0);
    STGB(0, 1, 0);
    STGA(0, 1, 0);
    EW4;

    const int NITER = K >> 7;
    for (int j = 0; j < NITER - 1; ++j) {
        const int ko = (j << 7) + 64;    // tile 2j+1 -> buf1
        const int kn = (j << 7) + 128;   // tile 2j+2 -> buf0
        PHASE(0,     0, 0, STGA(65536, 0, ko), EW4);
        PHASE(0,     0, 1, STGB(65536, 0, ko), EW4);
        PHASE(0,     1, 1, STGB(65536, 1, ko), EWN);
        PHASE(0,     1, 0, STGA(65536, 1, ko), EW4);
        PHASE(65536, 0, 0, STGA(0, 0, kn),     EW4);
        PHASE(65536, 0, 1, STGB(0, 0, kn),     EW4);
        PHASE(65536, 1, 1, STGB(0, 1, kn),     EWN);
        PHASE(65536, 1, 0, STGA(0, 1, kn),     EW4);
    }
    {   // last iteration: stage tile 2j+1 only; drain progressively
        const int ko = ((NITER - 1) << 7) + 64;
        PHASE(0,     0, 0, STGA(65536, 0, ko), EW4);
        PHASE(0,     0, 1, STGB(65536, 0, ko), EW4);
        PHASE(0,     1, 1, STGB(65536, 1, ko), EWN);
        PHASE(0,     1, 0, STGA(65536, 1, ko), EW4);
        PHASE(65536, 0, 0, (void)0,            EW2);
        PHASE(65536, 0, 1, (void)0,            EW0);
        PHASE(65536, 1, 1, (void)0,            EWN);
        PHASE(65536, 1, 0, (void)0,            EWN);
    }
#undef PHASE
#undef STGA
#undef STGB

    // ---- epilogue: D layout col=lane&15, row=(lane>>4)*4+reg
    const int erow = (bm << 8) + (wm << 7) + ((ln >> 4) << 2);
    const int ecol = (bn << 8) + (wn << 6) + (ln & 15);
    float bv[4];
#pragma unroll
    for (int n = 0; n < 4; ++n) bv[n] = bias[ecol + (n << 4)];
#pragma unroll
    for (int m = 0; m < 8; ++m)
#pragma unroll
        for (int r = 0; r < 4; ++r) {
            float* Crow = C + (size_t)(erow + (m << 4) + r) * N + ecol;
#pragma unroll
            for (int n = 0; n < 4; ++n)
                Crow[n << 4] = acc[m][n][r] + bv[n];
        }
}

// ---------------- Fallback: fused dequant+GEMM (no workspace) --------------
__global__ __launch_bounds__(256) void k_fused(
    const float* __restrict__ X, const int* __restrict__ Q,
    const float* __restrict__ SC, const float* __restrict__ bias,
    float* __restrict__ C, int M, int N, int K) {
    __shared__ __align__(16) bf16 sA[128 * 32];
    __shared__ __align__(16) bf16 sB[128 * 32];
    const int tid = threadIdx.x;
    const int wv = tid >> 6;
    const int ln = tid & 63;
    const int nbn = N >> 7;
    const int nwg = gridDim.x;
    const int q8 = nwg >> 3, r8 = nwg & 7;
    const int xcd = blockIdx.x & 7, lin = blockIdx.x >> 3;
    const int swz = (xcd < r8 ? xcd * (q8 + 1)
                              : r8 * (q8 + 1) + (xcd - r8) * q8) + lin;
    const int bm = swz / nbn, bn = swz % nbn;
    const int wr = (wv >> 1) << 6;
    const int wc = (wv & 1) << 6;
    const int srow = tid >> 1;
    const int sk = (tid & 1) << 4;

    f32x4 acc[4][4] = {};
    const float* xrow = X + (size_t)((bm << 7) + srow) * K + sk;
    const int* qrow = Q + (size_t)((bn << 7) + srow) * K + sk;
    const float* scrow = SC + (size_t)((bn << 7) + srow) * (K >> 5);

    for (int kt = 0; kt < K; kt += 32) {
        const float4 a0 = *(const float4*)(xrow + kt);
        const float4 a1 = *(const float4*)(xrow + kt + 4);
        const float4 a2 = *(const float4*)(xrow + kt + 8);
        const float4 a3 = *(const float4*)(xrow + kt + 12);
        const int4 q0 = *(const int4*)(qrow + kt);
        const int4 q1 = *(const int4*)(qrow + kt + 4);
        const int4 q2 = *(const int4*)(qrow + kt + 8);
        const int4 q3 = *(const int4*)(qrow + kt + 12);
        const float s = scrow[(kt + sk) >> 5];
        bf16x8 wa0, wa1, wb0, wb1;
        wa0[0] = (bf16)a0.x; wa0[1] = (bf16)a0.y; wa0[2] = (bf16)a0.z; wa0[3] = (bf16)a0.w;
        wa0[4] = (bf16)a1.x; wa0[5] = (bf16)a1.y; wa0[6] = (bf16)a1.z; wa0[7] = (bf16)a1.w;
        wa1[0] = (bf16)a2.x; wa1[1] = (bf16)a2.y; wa1[2] = (bf16)a2.z; wa1[3] = (bf16)a2.w;
        wa1[4] = (bf16)a3.x; wa1[5] = (bf16)a3.y; wa1[6] = (bf16)a3.z; wa1[7] = (bf16)a3.w;
        wb0[0] = (bf16)(q0.x * s); wb0[1] = (bf16)(q0.y * s);
        wb0[2] = (bf16)(q0.z * s); wb0[3] = (bf16)(q0.w * s);
        wb0[4] = (bf16)(q1.x * s); wb0[5] = (bf16)(q1.y * s);
        wb0[6] = (bf16)(q1.z * s); wb0[7] = (bf16)(q1.w * s);
        wb1[0] = (bf16)(q2.x * s); wb1[1] = (bf16)(q2.y * s);
        wb1[2] = (bf16)(q2.z * s); wb1[3] = (bf16)(q2.w * s);
        wb1[4] = (bf16)(q3.x * s); wb1[5] = (bf16)(q3.y * s);
        wb1[6] = (bf16)(q3.z * s); wb1[7] = (bf16)(q3.w * s);
        __syncthreads();
        *(bf16x8*)(sA + srow * 32 + sk) = wa0;
        *(bf16x8*)(sA + srow * 32 + sk + 8) = wa1;
        *(bf16x8*)(sB + srow * 32 + sk) = wb0;
        *(bf16x8*)(sB + srow * 32 + sk + 8) = wb1;
        __syncthreads();

        bf16x8 af[4], bg[4];
#pragma unroll
        for (int m = 0; m < 4; ++m)
            af[m] = *(const bf16x8*)(sA + ((wr + (m << 4) + (ln & 15)) << 5) +
                                     ((ln >> 4) << 3));
#pragma unroll
        for (int n = 0; n < 4; ++n)
            bg[n] = *(const bf16x8*)(sB + ((wc + (n << 4) + (ln & 15)) << 5) +
                                     ((ln >> 4) << 3));
#pragma unroll
        for (int m = 0; m < 4; ++m)
#pragma unroll
            for (int n = 0; n < 4; ++n)
                acc[m][n] = __builtin_amdgcn_mfma_f32_16x16x32_bf16(
                    af[m], bg[n], acc[m][n], 0, 0, 0);
    }

    float bv[4];
#pragma unroll
    for (int n = 0; n < 4; ++n)
        bv[n] = bias[(bn << 7) + wc + (n << 4) + (ln & 15)];
#pragma unroll
    for (int m = 0; m < 4; ++m) {
        const int grow0 = (bm << 7) + wr + (m << 4) + ((ln >> 4) << 2);
#pragma unroll
        for (int r = 0; r < 4; ++r) {
            float* Crow = C + (size_t)(grow0 + r) * N;
#pragma unroll
            for (int n = 0; n < 4; ++n)
                Crow[(bn << 7) + wc + (n << 4) + (ln & 15)] =
                    acc[m][n][r] + bv[n];
        }
    }
}

extern "C" void kernel_launch(void* const* d_in, const int* in_sizes, int n_in,
                              void* d_out, int out_size, void* d_ws, size_t ws_size,
                              hipStream_t stream) {
    const float* x = (const float*)d_in[0];
    const int* wq = (const int*)d_in[1];
    const float* sc = (const float*)d_in[2];
    const float* bias = (const float*)d_in[3];
    float* out = (float*)d_out;

    const long long xN = in_sizes[0];  // TOK*IN
    const long long wN = in_sizes[1];  // OUT*IN
    const int OUT = in_sizes[3];       // bias length
    const int IN = (int)(wN / OUT);
    const int TOK = (int)(xN / IN);
    const int M = TOK, N = OUT, K = IN;

    const size_t wb_bytes = (size_t)wN * 2;
    const size_t xb_bytes = (size_t)xN * 2;
    const bool ok8p = (M % 256 == 0) && (N % 256 == 0) && (K % 128 == 0);

    if (ok8p && ws_size >= wb_bytes + xb_bytes) {
        bf16* Wb = (bf16*)d_ws;
        bf16* Xb = (bf16*)((char*)d_ws + wb_bytes);
        dim3 dq_grid((IN / 8 + 127) / 128, OUT);
        k_dequant<<<dq_grid, 128, 0, stream>>>(wq, sc, Wb, IN);
        const long long n8 = xN / 8;
        int cvt_blocks = (int)((n8 + 255) / 256);
        if (cvt_blocks > 2048) cvt_blocks = 2048;
        k_cvt<<<cvt_blocks, 256, 0, stream>>>(x, Xb, n8);
        const int grid = (M / 256) * (N / 256);
        k_gemm8p<<<grid, 512, 0, stream>>>(Xb, Wb, bias, out, M, N, K);
    } else {
        const int grid = (M / 128) * (N / 128);
        k_fused<<<grid, 256, 0, stream>>>(x, wq, sc, bias, out, M, N, K);
    }
}

// Round 5
// 332.766 us; speedup vs baseline: 1.0876x; 1.0876x over previous
//
#include <hip/hip_runtime.h>
#include <hip/hip_bf16.h>
#include <stdint.h>

// DequantingLinear: out[TOK,OUT] = x[TOK,IN] @ dequant(w_q,w_scales)^T + bias
// R5: faithful m201-style 8-phase. Register-held fragment reuse (24 ds_read
// per K-tile per wave, spread 12/4/8/0 across 4 phases), 1 half-tile staged
// per phase with 3-6 phase lead, vmcnt(4) only at phases 4 and 8.

typedef __bf16 bf16;
typedef __bf16 bf16x8 __attribute__((ext_vector_type(8)));
typedef float f32x4 __attribute__((ext_vector_type(4)));

#define AS1 __attribute__((address_space(1)))
#define AS3 __attribute__((address_space(3)))

__device__ __forceinline__ void gload_lds16(const void* g, void* l) {
    __builtin_amdgcn_global_load_lds((AS1 void*)g, (AS3 void*)l, 16, 0, 0);
}

#define MFMA16(d, x, y) d = __builtin_amdgcn_mfma_f32_16x16x32_bf16(x, y, d, 0, 0, 0)

// ---------------- Pass 1a: dequantize w_q (int32) * scale -> bf16 ----------
__global__ __launch_bounds__(128) void k_dequant(
    const int* __restrict__ q, const float* __restrict__ sc,
    bf16* __restrict__ w, int IN) {
    const int row = blockIdx.y;
    const int k = (blockIdx.x * 128 + threadIdx.x) * 8;
    if (k >= IN) return;
    const float s = sc[(size_t)row * (IN >> 5) + (k >> 5)];
    const size_t base = (size_t)row * IN + k;
    const int4 q0 = *(const int4*)(q + base);
    const int4 q1 = *(const int4*)(q + base + 4);
    bf16x8 o;
    o[0] = (bf16)(q0.x * s); o[1] = (bf16)(q0.y * s);
    o[2] = (bf16)(q0.z * s); o[3] = (bf16)(q0.w * s);
    o[4] = (bf16)(q1.x * s); o[5] = (bf16)(q1.y * s);
    o[6] = (bf16)(q1.z * s); o[7] = (bf16)(q1.w * s);
    *(bf16x8*)(w + base) = o;
}

// ---------------- Pass 1b: x f32 -> bf16 -----------------------------------
__global__ __launch_bounds__(256) void k_cvt(
    const float* __restrict__ x, bf16* __restrict__ xb, long long n8) {
    long long i = (long long)blockIdx.x * 256 + threadIdx.x;
    const long long stride = (long long)gridDim.x * 256;
    for (; i < n8; i += stride) {
        const float4 a = *(const float4*)(x + i * 8);
        const float4 b = *(const float4*)(x + i * 8 + 4);
        bf16x8 o;
        o[0] = (bf16)a.x; o[1] = (bf16)a.y; o[2] = (bf16)a.z; o[3] = (bf16)a.w;
        o[4] = (bf16)b.x; o[5] = (bf16)b.y; o[6] = (bf16)b.z; o[7] = (bf16)b.w;
        *(bf16x8*)(xb + i * 8) = o;
    }
}

// ---------------- Pass 2: 256x256 bf16 GEMM, 8-phase with reg reuse --------
// 512 thr = 8 waves (wm=wv>>2, wn=wv&3); wave out 128x64.
// LDS per buf (64KB): A rows 0-255 linear @0 (row*128B, XOR-swizzled cols),
// B rows 0-255 linear @32768. Stage units = 128-row halves (16KB, 2 gloads).
// Quadrants per K-tile: (0,0) rd A0+B0, (0,1) rd B1, (1,1) rd A1, (1,0) rd 0.
// Stages/iter: ph1 Alo[T1] ph2 Ahi[T1] ph3 Blo[T2] ph4 Bhi[T2]+vmcnt(4)
//              ph5 Alo[T2] ph6 Ahi[T2] ph7 Blo[T3] ph8 Bhi[T3]+vmcnt(4).
__global__ __launch_bounds__(512, 2) void k_gemm8p(
    const bf16* __restrict__ A, const bf16* __restrict__ B,
    const float* __restrict__ bias, float* __restrict__ C,
    int M, int N, int K) {
    __shared__ __align__(16) char lds[131072];
    const int tid = threadIdx.x;
    const int wv = tid >> 6, ln = tid & 63;
    const int wm = wv >> 2, wn = wv & 3;
    const int nbn = N >> 8;
    const int nwg = gridDim.x;
    const int q8 = nwg >> 3, r8 = nwg & 7;
    const int xcd = blockIdx.x & 7, lin = blockIdx.x >> 3;
    const int swz = (xcd < r8 ? xcd * (q8 + 1)
                              : r8 * (q8 + 1) + (xcd - r8) * q8) + lin;
    const int bm = swz / nbn, bn = swz % nbn;

    const size_t rowb = (size_t)K * 2;
    const size_t r64 = (size_t)64 * rowb, r128 = (size_t)128 * rowb;
    const int scol = (((tid ^ (tid >> 3)) & 7) << 4);
    const char* Ag = (const char*)A + ((size_t)(bm << 8) + (tid >> 3)) * rowb + scol;
    const char* Bg = (const char*)B + ((size_t)(bn << 8) + (tid >> 3)) * rowb + scol;
    const char* Ah = Ag + r128;
    const char* Bh = Bg + r128;
    const int ldsw = wv << 10;

    // one half-tile (128 rows x 64 cols bf16 = 16KB) = 2 gload_lds
#define STGU(bb_, uo_, src_, kt_) do {                                        \
        const size_t kb_ = (size_t)(kt_) << 1;                                \
        gload_lds16((src_) + kb_, lds + (bb_) + (uo_) + ldsw);                \
        gload_lds16((src_) + r64 + kb_, lds + (bb_) + (uo_) + 8192 + ldsw);   \
    } while (0)

    // swizzled column bytes for kslice 0/1 (row&7 == ln&7 for all frag rows)
    const int c0 = ((ln & 4) << 4) | ((((ln >> 4) ^ ln) & 3) << 4);
    const int c1 = c0 ^ 64;
    const int arow = ((wm << 7) + (ln & 15)) << 7;            // + h*8192 + mm*2048
    const int brow = 32768 + (((wn << 6) + (ln & 15)) << 7);  // + n*2048

    f32x4 acc[8][4] = {};
    bf16x8 pa[8], pb0[4], pb1[4];

#define RDA(bb_, h_) do { _Pragma("unroll")                                   \
        for (int mm = 0; mm < 4; ++mm) {                                      \
            pa[mm*2+0] = *(const bf16x8*)(lds + (bb_) + arow + (h_)*8192 + mm*2048 + c0); \
            pa[mm*2+1] = *(const bf16x8*)(lds + (bb_) + arow + (h_)*8192 + mm*2048 + c1); \
        } } while (0)
#define RDB(bb_, c_, PB_) do { _Pragma("unroll")                              \
        for (int nn = 0; nn < 2; ++nn) {                                      \
            PB_[nn*2+0] = *(const bf16x8*)(lds + (bb_) + brow + ((c_)*2+nn)*2048 + c0); \
            PB_[nn*2+1] = *(const bf16x8*)(lds + (bb_) + brow + ((c_)*2+nn)*2048 + c1); \
        } } while (0)
#define CLUSTER(h_, c_, PB_) do {                                             \
        __builtin_amdgcn_s_setprio(1);                                        \
        _Pragma("unroll") for (int ks = 0; ks < 2; ++ks)                      \
            _Pragma("unroll") for (int mm = 0; mm < 4; ++mm)                  \
                _Pragma("unroll") for (int nn = 0; nn < 2; ++nn)              \
                    MFMA16(acc[(h_)*4+mm][(c_)*2+nn], pa[mm*2+ks], PB_[nn*2+ks]); \
        __builtin_amdgcn_s_setprio(0);                                        \
    } while (0)

#define BAR __builtin_amdgcn_s_barrier()
#define VMW4 asm volatile("s_waitcnt vmcnt(4)" ::: "memory")
#define VMW0 asm volatile("s_waitcnt vmcnt(0)" ::: "memory")

    // ---- prologue: tile0 -> buf0 (4 units), B halves of tile1 -> buf1
    STGU(0, 0,     Ag, 0);
    STGU(0, 16384, Ah, 0);
    STGU(0, 32768, Bg, 0);
    STGU(0, 49152, Bh, 0);
    STGU(65536, 32768, Bg, 64);
    STGU(65536, 49152, Bh, 64);
    VMW4;  // tile0 resident; B[T1] (4 loads) stay in flight
    BAR;

    const int NI = K >> 7;
    for (int j = 0; j < NI - 1; ++j) {
        const int kT1 = (j << 7) + 64, kT2 = kT1 + 64, kT3 = kT2 + 64;
        // ph1 (0,0)
        RDA(0, 0); RDB(0, 0, pb0); STGU(65536, 0, Ag, kT1);
        BAR; CLUSTER(0, 0, pb0); BAR;
        // ph2 (0,1)
        RDB(0, 1, pb1); STGU(65536, 16384, Ah, kT1);
        BAR; CLUSTER(0, 1, pb1); BAR;
        // ph3 (1,1)
        RDA(0, 1); STGU(0, 32768, Bg, kT2);
        BAR; CLUSTER(1, 1, pb1); BAR;
        // ph4 (1,0)
        STGU(0, 49152, Bh, kT2);
        BAR; CLUSTER(1, 0, pb0); VMW4; BAR;
        // ph5 (0,0) on buf1
        RDA(65536, 0); RDB(65536, 0, pb0); STGU(0, 0, Ag, kT2);
        BAR; CLUSTER(0, 0, pb0); BAR;
        // ph6 (0,1)
        RDB(65536, 1, pb1); STGU(0, 16384, Ah, kT2);
        BAR; CLUSTER(0, 1, pb1); BAR;
        // ph7 (1,1)
        RDA(65536, 1); STGU(65536, 32768, Bg, kT3);
        BAR; CLUSTER(1, 1, pb1); BAR;
        // ph8 (1,0)
        STGU(65536, 49152, Bh, kT3);
        BAR; CLUSTER(1, 0, pb0); VMW4; BAR;
    }
    {   // last iteration: tiles 2(NI-1) in buf0, T1=last in buf1
        const int kT1 = ((NI - 1) << 7) + 64;
        RDA(0, 0); RDB(0, 0, pb0); STGU(65536, 0, Ag, kT1);
        BAR; CLUSTER(0, 0, pb0); BAR;
        RDB(0, 1, pb1); STGU(65536, 16384, Ah, kT1);
        BAR; CLUSTER(0, 1, pb1); BAR;
        RDA(0, 1);
        BAR; CLUSTER(1, 1, pb1); BAR;
        BAR; CLUSTER(1, 0, pb0); VMW0; BAR;
        RDA(65536, 0); RDB(65536, 0, pb0);
        BAR; CLUSTER(0, 0, pb0); BAR;
        RDB(65536, 1, pb1);
        BAR; CLUSTER(0, 1, pb1); BAR;
        RDA(65536, 1);
        BAR; CLUSTER(1, 1, pb1); BAR;
        BAR; CLUSTER(1, 0, pb0); BAR;
    }
#undef STGU
#undef RDA
#undef RDB
#undef CLUSTER

    // ---- epilogue: D layout col=lane&15, row=(lane>>4)*4+reg
    const int erow = (bm << 8) + (wm << 7) + ((ln >> 4) << 2);
    const int ecol = (bn << 8) + (wn << 6) + (ln & 15);
    float bv[4];
#pragma unroll
    for (int n = 0; n < 4; ++n) bv[n] = bias[ecol + (n << 4)];
#pragma unroll
    for (int m = 0; m < 8; ++m)
#pragma unroll
        for (int r = 0; r < 4; ++r) {
            float* Crow = C + (size_t)(erow + (m << 4) + r) * N + ecol;
#pragma unroll
            for (int n = 0; n < 4; ++n)
                Crow[n << 4] = acc[m][n][r] + bv[n];
        }
}

// ---------------- Fallback: fused dequant+GEMM (no workspace) --------------
__global__ __launch_bounds__(256) void k_fused(
    const float* __restrict__ X, const int* __restrict__ Q,
    const float* __restrict__ SC, const float* __restrict__ bias,
    float* __restrict__ C, int M, int N, int K) {
    __shared__ __align__(16) bf16 sA[128 * 32];
    __shared__ __align__(16) bf16 sB[128 * 32];
    const int tid = threadIdx.x;
    const int wv = tid >> 6;
    const int ln = tid & 63;
    const int nbn = N >> 7;
    const int nwg = gridDim.x;
    const int q8 = nwg >> 3, r8 = nwg & 7;
    const int xcd = blockIdx.x & 7, lin = blockIdx.x >> 3;
    const int swz = (xcd < r8 ? xcd * (q8 + 1)
                              : r8 * (q8 + 1) + (xcd - r8) * q8) + lin;
    const int bm = swz / nbn, bn = swz % nbn;
    const int wr = (wv >> 1) << 6;
    const int wc = (wv & 1) << 6;
    const int srow = tid >> 1;
    const int sk = (tid & 1) << 4;

    f32x4 acc[4][4] = {};
    const float* xrow = X + (size_t)((bm << 7) + srow) * K + sk;
    const int* qrow = Q + (size_t)((bn << 7) + srow) * K + sk;
    const float* scrow = SC + (size_t)((bn << 7) + srow) * (K >> 5);

    for (int kt = 0; kt < K; kt += 32) {
        const float4 a0 = *(const float4*)(xrow + kt);
        const float4 a1 = *(const float4*)(xrow + kt + 4);
        const float4 a2 = *(const float4*)(xrow + kt + 8);
        const float4 a3 = *(const float4*)(xrow + kt + 12);
        const int4 q0 = *(const int4*)(qrow + kt);
        const int4 q1 = *(const int4*)(qrow + kt + 4);
        const int4 q2 = *(const int4*)(qrow + kt + 8);
        const int4 q3 = *(const int4*)(qrow + kt + 12);
        const float s = scrow[(kt + sk) >> 5];
        bf16x8 wa0, wa1, wb0, wb1;
        wa0[0] = (bf16)a0.x; wa0[1] = (bf16)a0.y; wa0[2] = (bf16)a0.z; wa0[3] = (bf16)a0.w;
        wa0[4] = (bf16)a1.x; wa0[5] = (bf16)a1.y; wa0[6] = (bf16)a1.z; wa0[7] = (bf16)a1.w;
        wa1[0] = (bf16)a2.x; wa1[1] = (bf16)a2.y; wa1[2] = (bf16)a2.z; wa1[3] = (bf16)a2.w;
        wa1[4] = (bf16)a3.x; wa1[5] = (bf16)a3.y; wa1[6] = (bf16)a3.z; wa1[7] = (bf16)a3.w;
        wb0[0] = (bf16)(q0.x * s); wb0[1] = (bf16)(q0.y * s);
        wb0[2] = (bf16)(q0.z * s); wb0[3] = (bf16)(q0.w * s);
        wb0[4] = (bf16)(q1.x * s); wb0[5] = (bf16)(q1.y * s);
        wb0[6] = (bf16)(q1.z * s); wb0[7] = (bf16)(q1.w * s);
        wb1[0] = (bf16)(q2.x * s); wb1[1] = (bf16)(q2.y * s);
        wb1[2] = (bf16)(q2.z * s); wb1[3] = (bf16)(q2.w * s);
        wb1[4] = (bf16)(q3.x * s); wb1[5] = (bf16)(q3.y * s);
        wb1[6] = (bf16)(q3.z * s); wb1[7] = (bf16)(q3.w * s);
        __syncthreads();
        *(bf16x8*)(sA + srow * 32 + sk) = wa0;
        *(bf16x8*)(sA + srow * 32 + sk + 8) = wa1;
        *(bf16x8*)(sB + srow * 32 + sk) = wb0;
        *(bf16x8*)(sB + srow * 32 + sk + 8) = wb1;
        __syncthreads();

        bf16x8 af[4], bg[4];
#pragma unroll
        for (int m = 0; m < 4; ++m)
            af[m] = *(const bf16x8*)(sA + ((wr + (m << 4) + (ln & 15)) << 5) +
                                     ((ln >> 4) << 3));
#pragma unroll
        for (int n = 0; n < 4; ++n)
            bg[n] = *(const bf16x8*)(sB + ((wc + (n << 4) + (ln & 15)) << 5) +
                                     ((ln >> 4) << 3));
#pragma unroll
        for (int m = 0; m < 4; ++m)
#pragma unroll
            for (int n = 0; n < 4; ++n)
                acc[m][n] = __builtin_amdgcn_mfma_f32_16x16x32_bf16(
                    af[m], bg[n], acc[m][n], 0, 0, 0);
    }

    float bv[4];
#pragma unroll
    for (int n = 0; n < 4; ++n)
        bv[n] = bias[(bn << 7) + wc + (n << 4) + (ln & 15)];
#pragma unroll
    for (int m = 0; m < 4; ++m) {
        const int grow0 = (bm << 7) + wr + (m << 4) + ((ln >> 4) << 2);
#pragma unroll
        for (int r = 0; r < 4; ++r) {
            float* Crow = C + (size_t)(grow0 + r) * N;
#pragma unroll
            for (int n = 0; n < 4; ++n)
                Crow[(bn << 7) + wc + (n << 4) + (ln & 15)] =
                    acc[m][n][r] + bv[n];
        }
    }
}

extern "C" void kernel_launch(void* const* d_in, const int* in_sizes, int n_in,
                              void* d_out, int out_size, void* d_ws, size_t ws_size,
                              hipStream_t stream) {
    const float* x = (const float*)d_in[0];
    const int* wq = (const int*)d_in[1];
    const float* sc = (const float*)d_in[2];
    const float* bias = (const float*)d_in[3];
    float* out = (float*)d_out;

    const long long xN = in_sizes[0];  // TOK*IN
    const long long wN = in_sizes[1];  // OUT*IN
    const int OUT = in_sizes[3];       // bias length
    const int IN = (int)(wN / OUT);
    const int TOK = (int)(xN / IN);
    const int M = TOK, N = OUT, K = IN;

    const size_t wb_bytes = (size_t)wN * 2;
    const size_t xb_bytes = (size_t)xN * 2;
    const bool ok8p = (M % 256 == 0) && (N % 256 == 0) && (K % 128 == 0) &&
                      (K >= 256);

    if (ok8p && ws_size >= wb_bytes + xb_bytes) {
        bf16* Wb = (bf16*)d_ws;
        bf16* Xb = (bf16*)((char*)d_ws + wb_bytes);
        dim3 dq_grid((IN / 8 + 127) / 128, OUT);
        k_dequant<<<dq_grid, 128, 0, stream>>>(wq, sc, Wb, IN);
        const long long n8 = xN / 8;
        int cvt_blocks = (int)((n8 + 255) / 256);
        if (cvt_blocks > 2048) cvt_blocks = 2048;
        k_cvt<<<cvt_blocks, 256, 0, stream>>>(x, Xb, n8);
        const int grid = (M / 256) * (N / 256);
        k_gemm8p<<<grid, 512, 0, stream>>>(Xb, Wb, bias, out, M, N, K);
    } else {
        const int grid = (M / 128) * (N / 128);
        k_fused<<<grid, 256, 0, stream>>>(x, wq, sc, bias, out, M, N, K);
    }
}